// Round 4
// baseline (336.106 us; speedup 1.0000x reference)
//
#include <hip/hip_runtime.h>
#include <hip/hip_bf16.h>
#include <stdint.h>

typedef __hip_bfloat16 bf16;
typedef __attribute__((ext_vector_type(8))) short v8s;   // 8 bf16 in 4 VGPRs
typedef __attribute__((ext_vector_type(4))) float v4f;   // MFMA C/D frag

__device__ __forceinline__ bf16 tob(float x) { return __float2bfloat16(x); }

// async global->LDS, 16B/lane; LDS dest = wave-uniform base + lane*16
__device__ __forceinline__ void gload16(const void* g, void* l) {
  __builtin_amdgcn_global_load_lds(
      (const __attribute__((address_space(1))) uint32_t*)g,
      (__attribute__((address_space(3))) uint32_t*)l,
      16, 0, 0);
}

// sum over the 16 lanes of a DPP row (lanes [q*16, q*16+16)), VALU-pipe only:
// v += ror1; v += ror2; v += ror4; v += ror8  -> all 16 lanes hold the row-sum
__device__ __forceinline__ float rsum16(float v) {
  union { float f; int i; } u, w;
  u.f = v;
  w.i = __builtin_amdgcn_update_dpp(u.i, u.i, 0x121, 0xf, 0xf, false); u.f += w.f;
  w.i = __builtin_amdgcn_update_dpp(u.i, u.i, 0x122, 0xf, 0xf, false); u.f += w.f;
  w.i = __builtin_amdgcn_update_dpp(u.i, u.i, 0x124, 0xf, 0xf, false); u.f += w.f;
  w.i = __builtin_amdgcn_update_dpp(u.i, u.i, 0x128, 0xf, 0xf, false); u.f += w.f;
  return u.f;
}

// ============ merged prep kernel: role by blockIdx ============
// [0,512): lin1   [512,768): gp   [768,1024): w2t   [1024,1056): G
__global__ void k_prep(const float* __restrict__ fea, const float* __restrict__ Wl1,
                       const float* __restrict__ bl1, const float* __restrict__ Wc1,
                       const float* __restrict__ bc1, const float* __restrict__ Wc2,
                       float* __restrict__ h1, float* __restrict__ gp,
                       bf16* __restrict__ W2T, float* __restrict__ G) {
  const int blk = blockIdx.x;
  if (blk < 512) {                     // ---- lin1: h1 = relu(fea@Wl1 + bl1)
    __shared__ float red[256];
    const int nl = threadIdx.x & 15, ks = threadIdx.x >> 4;
    const int o = blk * 16 + nl;
    const int b = o >> 10, n = o & 1023;
    const float* fr = fea + (b << 10) + ks * 64;
    const float* wp = Wl1 + (size_t)(ks * 64) * 1024 + n;
    float acc = 0.f;
#pragma unroll 8
    for (int j = 0; j < 64; ++j) acc = fmaf(fr[j], wp[(size_t)j * 1024], acc);
    red[threadIdx.x] = acc;
    __syncthreads();
    if (threadIdx.x < 16) {
      float s = bl1[n];
#pragma unroll
      for (int i = 0; i < 16; ++i) s += red[i * 16 + threadIdx.x];
      h1[o] = fmaxf(s, 0.f);
    }
  } else if (blk < 768) {              // ---- gp = fea@Wc1[5:] + bc1
    __shared__ float red[256];
    const int nl = threadIdx.x & 15, ks = threadIdx.x >> 4;
    const int o = (blk - 512) * 16 + nl;
    const int b = o >> 9, n = o & 511;
    const float* fr = fea + (b << 10) + ks * 64;
    const float* wp = Wc1 + (size_t)(5 + ks * 64) * 512 + n;
    float acc = 0.f;
#pragma unroll 8
    for (int j = 0; j < 64; ++j) acc = fmaf(fr[j], wp[(size_t)j * 512], acc);
    red[threadIdx.x] = acc;
    __syncthreads();
    if (threadIdx.x < 16) {
      float s = bc1[n];
#pragma unroll
      for (int i = 0; i < 16; ++i) s += red[i * 16 + threadIdx.x];
      gp[o] = s;
    }
  } else if (blk < 1024) {             // ---- W2T[n,k] = bf16(Wc2[k,n])
    __shared__ float tile[32][33];
    const int id = blk - 768;
    const int bx = id & 15, by = id >> 4;
    const int c = threadIdx.x & 31, r8 = threadIdx.x >> 5;
#pragma unroll
    for (int i = 0; i < 4; ++i) {
      int r = r8 + i * 8;
      tile[r][c] = Wc2[(by * 32 + r) * 512 + bx * 32 + c];
    }
    __syncthreads();
#pragma unroll
    for (int i = 0; i < 4; ++i) {
      int r = r8 + i * 8;
      W2T[(size_t)(bx * 32 + r) * 512 + by * 32 + c] = tob(tile[c][r]);
    }
  } else {                             // ---- G[g,k] = gx*w0[k] + gy*w1[k]
    const int idx = (blk - 1024) * 256 + threadIdx.x;   // 8192 = 16*512
    const int g = idx >> 9, k = idx & 511;
    const float gx = -0.05f + (float)(g & 3) * (0.1f / 3.0f);
    const float gy = -0.05f + (float)(g >> 2) * (0.1f / 3.0f);
    G[idx] = gx * Wc1[k] + gy * Wc1[512 + k];
  }
}

// ============ x = h1 @ W_l2 + b_l2; also seeds fine = x + bc3 ============
__global__ void k_lin2(const float* __restrict__ h1, const float* __restrict__ W,
                       const float* __restrict__ bias, const float* __restrict__ bc3,
                       float* __restrict__ xf, float* __restrict__ xout,
                       float* __restrict__ fine) {
  __shared__ float red[256];
  const int nl = threadIdx.x & 15, ks = threadIdx.x >> 4;
  const int o = blockIdx.x * 16 + nl;            // 0..24575
  const int b = o / 3072, n = o - b * 3072;
  const float* hr = h1 + (b << 10) + ks * 64;
  const float* wp = W + (size_t)(ks * 64) * 3072 + n;
  float acc = 0.f;
#pragma unroll 8
  for (int j = 0; j < 64; ++j) acc = fmaf(hr[j], wp[(size_t)j * 3072], acc);
  red[threadIdx.x] = acc;
  __syncthreads();
  if (threadIdx.x < 16) {
    float s = bias[n];
#pragma unroll
    for (int i = 0; i < 16; ++i) s += red[i * 16 + threadIdx.x];
    xf[o] = s;
    xout[o] = s;
    const int c = n / 3, j = n - c * 3;          // x[b][c][j]
    const float seed = s + bc3[j];
    float* fp = fine + ((size_t)b * 16384 + c * 16) * 3 + j;
#pragma unroll
    for (int g = 0; g < 16; ++g) fp[g * 3] = seed;
  }
}

// ============ T[b,c,k] = gp[b,k] + x·Wc1[2:5,k]   (8,1024,512) f32 ============
__global__ void k_T(const float* __restrict__ gp, const float* __restrict__ xf,
                    const float* __restrict__ Wc1, float* __restrict__ T) {
  const int f4 = blockIdx.x * 256 + threadIdx.x;   // one float4 each; 1048576
  const int row = f4 >> 7, k4 = (f4 & 127) << 2;
  const int b = row >> 10, c = row & 1023;
  const float* xp = xf + (b * 1024 + c) * 3;
  const float x0 = xp[0], x1 = xp[1], x2 = xp[2];
  float4 gv = *(const float4*)(gp + (b << 9) + k4);
  float4 w2 = *(const float4*)(Wc1 + 2 * 512 + k4);
  float4 w3 = *(const float4*)(Wc1 + 3 * 512 + k4);
  float4 w4 = *(const float4*)(Wc1 + 4 * 512 + k4);
  float4 o;
  o.x = fmaf(x2, w4.x, fmaf(x1, w3.x, fmaf(x0, w2.x, gv.x)));
  o.y = fmaf(x2, w4.y, fmaf(x1, w3.y, fmaf(x0, w2.y, gv.y)));
  o.z = fmaf(x2, w4.z, fmaf(x1, w3.z, fmaf(x0, w2.z, gv.z)));
  o.w = fmaf(x2, w4.w, fmaf(x1, w3.w, fmaf(x0, w2.w, gv.w)));
  *(float4*)(T + (size_t)row * 512 + k4) = o;
}

// ============ barrier-free fused GEMM + conv3 epilogue ============
// 256 blocks x 512 thr. Block = (Nchunk = blk>>6)*128 cols, (Mgrp = blk&63)*2048 rows.
// Bs: BN=128 x K=512 bf16, rows padded to 1040 B (2-way max bank aliasing = free).
// A-frags built in registers from T+G (g == lm by construction). No __syncthreads
// after the initial Bs load -> no barrier/vmcnt drains in the M/K loops.
__global__ __launch_bounds__(512, 2)
void k_gemm(const bf16* __restrict__ W2T, const float* __restrict__ T,
            const float* __restrict__ G, const float* __restrict__ bc2,
            const float* __restrict__ Wc3, float* __restrict__ fine) {
  __shared__ __align__(16) bf16 Bs[128 * 520];     // 133120 B
  const int t = threadIdx.x;
  const int w = t >> 6, l = t & 63, q = l >> 4, lm = l & 15;
  const int wr = (w >> 1) * 64;                    // row-group base: 0/64/128/192
  const int wc = (w & 1) * 64;                     // col-group base: 0/64
  const int Mgrp = blockIdx.x & 63;
  const int Nbase = (blockIdx.x >> 6) * 128;       // same-Mgrp chunks 64 apart -> same XCD

  // stage Bs once: wave w loads B rows [w*16, w*16+16)
  {
    const char* src = (const char*)W2T + (size_t)(Nbase + w * 16) * 1024 + l * 16;
    char* dst = (char*)Bs + (w * 16) * 1040 + l * 16;
#pragma unroll
    for (int r = 0; r < 16; ++r)
      gload16(src + r * 1024, dst + r * 1040);
  }

  // hoisted per-lane epilogue constants (same n for every M-tile)
  float bv[4], w3c[4][3];
#pragma unroll
  for (int ni = 0; ni < 4; ++ni) {
    const int n = Nbase + wc + ni * 16 + lm;
    bv[ni] = bc2[n];
    w3c[ni][0] = Wc3[n * 3 + 0];
    w3c[ni][1] = Wc3[n * 3 + 1];
    w3c[ni][2] = Wc3[n * 3 + 2];
  }
  const float* Grow = G + lm * 512;                // g == lm for all our rows

  __syncthreads();                                 // Bs ready (only barrier)

  for (int mt = 0; mt < 8; ++mt) {
    const int m_base = Mgrp * 2048 + mt * 256 + wr;
    const int brow = m_base >> 14;
    const float* Trow[4];
#pragma unroll
    for (int mi = 0; mi < 4; ++mi) {
      const int c = ((m_base + mi * 16) >> 4) & 1023;
      Trow[mi] = T + ((size_t)(brow << 10) + c) * 512;
    }
    v4f acc[4][4];
#pragma unroll
    for (int mi = 0; mi < 4; ++mi)
#pragma unroll
      for (int ni = 0; ni < 4; ++ni) acc[mi][ni] = (v4f){0.f, 0.f, 0.f, 0.f};

#pragma unroll 2
    for (int kt = 0; kt < 16; ++kt) {
      const int k0 = kt * 32 + q * 8;
      const float4 g0 = *(const float4*)(Grow + k0);
      const float4 g1 = *(const float4*)(Grow + k0 + 4);
      v8s af[4];
#pragma unroll
      for (int mi = 0; mi < 4; ++mi) {
        const float4 t0 = *(const float4*)(Trow[mi] + k0);
        const float4 t1 = *(const float4*)(Trow[mi] + k0 + 4);
        union { bf16 h[8]; v8s v; } A;
        A.h[0] = tob(fmaxf(t0.x + g0.x, 0.f));
        A.h[1] = tob(fmaxf(t0.y + g0.y, 0.f));
        A.h[2] = tob(fmaxf(t0.z + g0.z, 0.f));
        A.h[3] = tob(fmaxf(t0.w + g0.w, 0.f));
        A.h[4] = tob(fmaxf(t1.x + g1.x, 0.f));
        A.h[5] = tob(fmaxf(t1.y + g1.y, 0.f));
        A.h[6] = tob(fmaxf(t1.z + g1.z, 0.f));
        A.h[7] = tob(fmaxf(t1.w + g1.w, 0.f));
        af[mi] = A.v;
      }
      v8s bf4[4];
#pragma unroll
      for (int ni = 0; ni < 4; ++ni)
        bf4[ni] = *(const v8s*)((const char*)Bs + (wc + ni * 16 + lm) * 1040 + kt * 64 + q * 16);
#pragma unroll
      for (int mi = 0; mi < 4; ++mi)
#pragma unroll
        for (int ni = 0; ni < 4; ++ni)
          acc[mi][ni] = __builtin_amdgcn_mfma_f32_16x16x32_bf16(af[mi], bf4[ni], acc[mi][ni], 0, 0, 0);
    }

    // epilogue: h2 = relu(acc + bc2); conv3 partials; DPP row-reduce; atomic into fine
#pragma unroll
    for (int mi = 0; mi < 4; ++mi) {
      float p[4][3];
#pragma unroll
      for (int r = 0; r < 4; ++r) { p[r][0] = 0.f; p[r][1] = 0.f; p[r][2] = 0.f; }
#pragma unroll
      for (int ni = 0; ni < 4; ++ni)
#pragma unroll
        for (int r = 0; r < 4; ++r) {
          const float v = fmaxf(acc[mi][ni][r] + bv[ni], 0.f);
          p[r][0] = fmaf(v, w3c[ni][0], p[r][0]);
          p[r][1] = fmaf(v, w3c[ni][1], p[r][1]);
          p[r][2] = fmaf(v, w3c[ni][2], p[r][2]);
        }
#pragma unroll
      for (int r = 0; r < 4; ++r)
#pragma unroll
        for (int j = 0; j < 3; ++j) {
          const float s = rsum16(p[r][j]);
          if (lm == 0)
            atomicAdd(&fine[(size_t)(m_base + mi * 16 + q * 4 + r) * 3 + j], s);
        }
    }
  }
}

extern "C" void kernel_launch(void* const* d_in, const int* in_sizes, int n_in,
                              void* d_out, int out_size, void* d_ws, size_t ws_size,
                              hipStream_t stream) {
  const float* fea = (const float*)d_in[0];
  const float* Wl1 = (const float*)d_in[1];
  const float* bl1 = (const float*)d_in[2];
  const float* Wl2 = (const float*)d_in[3];
  const float* bl2 = (const float*)d_in[4];
  const float* Wc1 = (const float*)d_in[5];
  const float* bc1 = (const float*)d_in[6];
  const float* Wc2 = (const float*)d_in[7];
  const float* bc2 = (const float*)d_in[8];
  const float* Wc3 = (const float*)d_in[9];
  const float* bc3 = (const float*)d_in[10];
  float* xout = (float*)d_out;                 // (8,1024,3)
  float* fine = (float*)d_out + 24576;         // (8,16384,3)
  char* ws = (char*)d_ws;
  float* h1  = (float*)ws;                     // 32 KB
  float* xf  = (float*)(ws + 32768);           // 96 KB
  float* gp  = (float*)(ws + 131072);          // 16 KB
  bf16*  W2T = (bf16*)(ws + 147456);           // 512 KB
  float* G   = (float*)(ws + 671744);          // 32 KB
  float* T   = (float*)(ws + 704512);          // 16 MB

  k_prep<<<1056, 256, 0, stream>>>(fea, Wl1, bl1, Wc1, bc1, Wc2, h1, gp, W2T, G);
  k_lin2<<<1536, 256, 0, stream>>>(h1, Wl2, bl2, bc3, xf, xout, fine);
  k_T<<<4096, 256, 0, stream>>>(gp, xf, Wc1, T);
  k_gemm<<<256, 512, 0, stream>>>(W2T, T, G, bc2, Wc3, fine);
}